// Round 9
// baseline (958.191 us; speedup 1.0000x reference)
//
#include <hip/hip_runtime.h>

// Problem constants
#define Bz 2048
#define Tz 336
#define Fz 10
#define H1 70
#define H2 21

typedef __attribute__((ext_vector_type(8))) short short8;   // 8 bf16 = 4 VGPR
typedef __attribute__((ext_vector_type(4))) float float4v;  // MFMA acc

#define MFMA16(a, b, c) __builtin_amdgcn_mfma_f32_16x16x32_bf16((a), (b), (c), 0, 0, 0)

__device__ __forceinline__ float sigf(float x) {
    return 1.0f / (1.0f + __expf(-x));
}
__device__ __forceinline__ float tanhfast(float x) {
    float t = __expf(2.0f * x);
    return 1.0f - 2.0f / (t + 1.0f);
}
__device__ __forceinline__ unsigned short f2bf(float v) {
    unsigned int u = __float_as_uint(v);
    u += 0x7FFFu + ((u >> 16) & 1u);
    return (unsigned short)(u >> 16);
}
__device__ __forceinline__ float bf2f(unsigned short s) {
    return __uint_as_float(((unsigned int)s) << 16);
}

// Fragment-order LDS offset (in shorts) for (index-in-16 m, k):
// (m, k) lives at ((k>>3)*16 + m)*8 + (k&7)
__device__ __forceinline__ int frag_off(int m, int k) {
    return (k >> 3) * 128 + m * 8 + (k & 7);
}

// ---------------------------------------------------------------------------
// Layer 1 (MFMA, D = W x h): input F=10, hidden 70.
// Grid 512 = 2 dir x 256 tiles of 8 batch rows -> 2 independent blocks/CU.
// 576 threads = 9 waves; 18 M-tiles = EXACTLY 2 tiles/wave (pA=2w, pB=2w+1).
//   K: 0..69 = h, 70..79 = x, 80 = bias slot (B side 1.0), 81..95 = 0.
// B-operand columns: batch rows DUPLICATED into cols 0..7 and 8..15, so
// every D column is a valid batch row. (Round-8 bug: cols 8..15 were zero,
// so lanes n>=8 computed bias-only gates — fixed by the duplication.)
// Dual-tile epilogue: lane n<8 -> tile A cell (m=n, u=4pA+quad),
// n>=8 -> tile B cell (m=n-8, u=4pB+quad); acc col n = batch (n&7) in both
// halves. Each lane runs ONE transcendental block; h written to both column
// copies (2x ds_write_b16). One barrier/step; x prefetch depth 2.
// y1 layout: [T][128][140][16] bf16 (8-row halves interleave via tb8&1).
// ---------------------------------------------------------------------------
__global__ __launch_bounds__(576, 5) void k_lstm1(
    const float* __restrict__ x,
    const float* __restrict__ wih_f, const float* __restrict__ whh_f,
    const float* __restrict__ bih_f, const float* __restrict__ bhh_f,
    const float* __restrict__ wih_b, const float* __restrict__ whh_b,
    const float* __restrict__ bih_b, const float* __restrict__ bhh_b,
    unsigned short* __restrict__ y1)
{
    __shared__ short hB_hi[2][1536];   // 96 k x 16 cols, frag order, dbuf

    const int tb8 = blockIdx.x & 255;  // 8-row tile index
    const int dir = blockIdx.x >> 8;
    const int b0  = tb8 << 3;
    const float* wih = dir ? wih_b : wih_f;
    const float* whh = dir ? whh_b : whh_f;
    const float* bih = dir ? bih_b : bih_f;
    const float* bhh = dir ? bhh_b : bhh_f;

    const int tid  = threadIdx.x;
    const int wv   = tid >> 6;        // 0..8
    const int lane = tid & 63;
    const int n    = lane & 15;
    const int quad = lane >> 4;

    // ---- W-side (A-operand) preload: tiles pA = 2wv, pB = 2wv+1, hi+lo ----
    short8 whi[2][3], wlo[2][3];
    const int g_ = n & 3;
#pragma unroll
    for (int tt = 0; tt < 2; ++tt) {
        const int p  = 2 * wv + tt;
        const int uu = 4 * p + (n >> 2);
#pragma unroll
        for (int q = 0; q < 3; ++q) {
#pragma unroll
            for (int j = 0; j < 8; ++j) {
                int k = q * 32 + quad * 8 + j;
                float v = 0.0f;
                if (uu < H1) {
                    int row = g_ * H1 + uu;
                    if (k < H1)        v = whh[row * H1 + k];
                    else if (k < 80)   v = wih[row * Fz + (k - H1)];
                    else if (k == 80)  v = bih[row] + bhh[row];
                }
                unsigned short hi = f2bf(v);
                unsigned short lo = f2bf(v - bf2f(hi));
                whi[tt][q][j] = (short)hi;
                wlo[tt][q][j] = (short)lo;
            }
        }
    }

    // ---- init LDS ----
    for (int e = tid; e < 1536; e += 576) {
        hB_hi[0][e] = 0; hB_hi[1][e] = 0;
    }
    __syncthreads();
    if (tid < 16) {
        int off = 1280 + tid * 8;       // frag_off(tid, 80)
        hB_hi[0][off] = (short)0x3F80;  // bf16(1.0) bias const, both col copies
        hB_hi[1][off] = (short)0x3F80;
    }

    // ---- stagers: 80 tasks (8 m x 10 f), 9 lanes per wave ----
    const int st  = wv * 9 + lane;
    const bool stg = (lane < 9) && (st < 80);
    int sm = 0, sf = 0;
    if (stg) { sm = st / Fz; sf = st % Fz; }

    // prologue: stage x(t0) into buf 0 (both col copies); preload x(t1)
    float xv = 0.0f;
    {
        const int t0 = dir ? (Tz - 1) : 0;
        if (stg) {
            float v = x[((size_t)(b0 + sm) * Tz + t0) * Fz + sf];
            unsigned short hv = f2bf(v);
            hB_hi[0][frag_off(sm,     H1 + sf)] = (short)hv;
            hB_hi[0][frag_off(sm + 8, H1 + sf)] = (short)hv;
            const int t1 = dir ? (Tz - 2) : 1;
            xv = x[((size_t)(b0 + sm) * Tz + t1) * Fz + sf];
        }
    }

    // dual-tile epilogue constants for this lane
    const int m8   = n & 7;
    const bool selB = (n >> 3) != 0;
    const int u    = 4 * (2 * wv + (selB ? 1 : 0)) + quad;   // cell index
    const bool val = (u < H1);

    float cst = 0.0f;

    for (int step = 0; step < Tz; ++step) {
        const int t  = dir ? (Tz - 1 - step) : step;
        const int pp = step & 1;
        __syncthreads();   // only barrier: buf[pp] complete, buf[pp^1] free

        // write x(t+1) from regs (both copies), then issue load x(t+2)
        if (stg && step + 1 < Tz) {
            unsigned short hv = f2bf(xv);
            hB_hi[pp ^ 1][frag_off(sm,     H1 + sf)] = (short)hv;
            hB_hi[pp ^ 1][frag_off(sm + 8, H1 + sf)] = (short)hv;
        }
        if (stg && step + 2 < Tz) {
            const int t2 = dir ? (t - 2) : (t + 2);
            xv = x[((size_t)(b0 + sm) * Tz + t2) * Fz + sf];
        }

        // B-operand frags from LDS (hi only)
        short8 bhi[3];
#pragma unroll
        for (int q = 0; q < 3; ++q)
            bhi[q] = *(const short8*)&hB_hi[pp][q * 512 + lane * 8];

        // MFMA: 2 tiles x (hi chain 3 + lo chain 3)
        float4v accA[2], accB[2];
#pragma unroll
        for (int tt = 0; tt < 2; ++tt) {
            accA[tt] = (float4v){0.f, 0.f, 0.f, 0.f};
            accB[tt] = (float4v){0.f, 0.f, 0.f, 0.f};
        }
#pragma unroll
        for (int tt = 0; tt < 2; ++tt) {
            accA[tt] = MFMA16(whi[tt][0], bhi[0], accA[tt]);
            accB[tt] = MFMA16(wlo[tt][0], bhi[0], accB[tt]);
            accA[tt] = MFMA16(whi[tt][1], bhi[1], accA[tt]);
            accB[tt] = MFMA16(wlo[tt][1], bhi[1], accB[tt]);
            accA[tt] = MFMA16(whi[tt][2], bhi[2], accA[tt]);
            accB[tt] = MFMA16(wlo[tt][2], bhi[2], accB[tt]);
        }

        // dual-tile in-lane epilogue: acc col n = batch (n&7) in both halves
        if (val) {
            float gi = selB ? (accA[1][0] + accB[1][0]) : (accA[0][0] + accB[0][0]);
            float gf = selB ? (accA[1][1] + accB[1][1]) : (accA[0][1] + accB[0][1]);
            float gc = selB ? (accA[1][2] + accB[1][2]) : (accA[0][2] + accB[0][2]);
            float go = selB ? (accA[1][3] + accB[1][3]) : (accA[0][3] + accB[0][3]);
            float cn = sigf(gf) * cst + sigf(gi) * tanhfast(gc);
            float h  = sigf(go) * tanhfast(cn);
            cst = cn;
            unsigned short hh = f2bf(h);
            hB_hi[pp ^ 1][frag_off(m8,     u)] = (short)hh;
            hB_hi[pp ^ 1][frag_off(m8 + 8, u)] = (short)hh;
            y1[(((size_t)t * 128 + (tb8 >> 1)) * 140 + dir * H1 + u) * 16
               + (tb8 & 1) * 8 + m8] = hh;
        }
    }
}

// ---------------------------------------------------------------------------
// Layer 2 (MFMA, D = W x h): input 140 (bf16 y1 [T][128][140][16]), hidden 21.
// Grid 256 = 2 dir x 128 tiles of 16 rows. 512 threads = 8 waves.
//   waves 0..5 compute tile p = wv (u = 4p+quad); threads 232..511 stage x.
//   K: 0..20 = h, 21 = bias slot, 22..31 = 0, 32..171 = x, 172..191 = 0.
// h/x are bf16 hi-only in LDS; W-lo kept ONLY for the h chunk (q=0):
// 7 MFMA/wave.
// ---------------------------------------------------------------------------
__global__ __launch_bounds__(512, 2) void k_lstm2(
    const unsigned short* __restrict__ y1,
    const float* __restrict__ wih_f, const float* __restrict__ whh_f,
    const float* __restrict__ bih_f, const float* __restrict__ bhh_f,
    const float* __restrict__ wih_b, const float* __restrict__ whh_b,
    const float* __restrict__ bih_b, const float* __restrict__ bhh_b,
    unsigned short* __restrict__ y2)   // [B][T][42] bf16
{
    __shared__ short hB_hi[2][3072];   // 192 k x 16 batch

    const int tb  = blockIdx.x & 127;
    const int dir = blockIdx.x >> 7;
    const int b0  = tb << 4;
    const float* wih = dir ? wih_b : wih_f;
    const float* whh = dir ? whh_b : whh_f;
    const float* bih = dir ? bih_b : bih_f;
    const float* bhh = dir ? bhh_b : bhh_f;

    const int tid  = threadIdx.x;
    const int wv   = tid >> 6;
    const int lane = tid & 63;
    const int n    = lane & 15;
    const int quad = lane >> 4;
    const bool comp = (wv < 6);

    // ---- W-side preload (waves 0..5): hi for all chunks, lo for chunk 0 ----
    short8 whi[6], wlo0;
    const int g_ = n & 3;
    if (comp) {
        const int uu = 4 * wv + (n >> 2);
#pragma unroll
        for (int q = 0; q < 6; ++q) {
#pragma unroll
            for (int j = 0; j < 8; ++j) {
                int k = q * 32 + quad * 8 + j;
                float v = 0.0f;
                if (uu < H2) {
                    int row = g_ * H2 + uu;
                    if (k < H2)                   v = whh[row * H2 + k];
                    else if (k == 21)             v = bih[row] + bhh[row];
                    else if (k >= 32 && k < 172)  v = wih[row * 140 + (k - 32)];
                }
                unsigned short hi = f2bf(v);
                whi[q][j] = (short)hi;
                if (q == 0) wlo0[j] = (short)f2bf(v - bf2f(hi));
            }
        }
    }

    // ---- init LDS ----
    for (int e = tid; e < 3072; e += 512) { hB_hi[0][e] = 0; hB_hi[1][e] = 0; }
    __syncthreads();
    if (tid < 16) {
        int off = frag_off(tid, 21);
        hB_hi[0][off] = (short)0x3F80;   // bias const 1.0
        hB_hi[1][off] = (short)0x3F80;
    }

    // ---- stager threads: es in [0,280); each loads 16B (8 ushorts) ----
    const int es = tid - 232;
    const bool stg = (es >= 0 && es < 280);

    // prologue: stage x(t0) into buf 0; preload x(t1) into regs
    short8 xr = (short8){0,0,0,0,0,0,0,0};
    {
        const int t0 = dir ? (Tz - 1) : 0;
        if (stg) {
            short8 v = *(const short8*)(y1 + ((size_t)t0 * 128 + tb) * 2240 + es * 8);
#pragma unroll
            for (int j = 0; j < 8; ++j) {
                int idx = es * 8 + j;
                hB_hi[0][frag_off(idx & 15, 32 + (idx >> 4))] = v[j];
            }
            const int t1 = dir ? (Tz - 2) : 1;
            xr = *(const short8*)(y1 + ((size_t)t1 * 128 + tb) * 2240 + es * 8);
        }
    }

    float cst = 0.0f;

    for (int step = 0; step < Tz; ++step) {
        const int t  = dir ? (Tz - 1 - step) : step;
        const int pp = step & 1;
        __syncthreads();

        // write x(t+1) from regs, then issue load x(t+2)
        if (stg && step + 1 < Tz) {
#pragma unroll
            for (int j = 0; j < 8; ++j) {
                int idx = es * 8 + j;
                hB_hi[pp ^ 1][frag_off(idx & 15, 32 + (idx >> 4))] = xr[j];
            }
        }
        if (stg && step + 2 < Tz) {
            const int t2 = dir ? (t - 2) : (t + 2);
            xr = *(const short8*)(y1 + ((size_t)t2 * 128 + tb) * 2240 + es * 8);
        }

        if (comp) {
            // B-operand frags (hi only)
            short8 bhi[6];
#pragma unroll
            for (int q = 0; q < 6; ++q)
                bhi[q] = *(const short8*)&hB_hi[pp][q * 512 + lane * 8];

            // 7 products, 2 independent chains (A: 3, B: 4)
            float4v accA = (float4v){0.f, 0.f, 0.f, 0.f};
            float4v accB = (float4v){0.f, 0.f, 0.f, 0.f};
            accA = MFMA16(whi[0], bhi[0], accA);
            accB = MFMA16(wlo0,   bhi[0], accB);
            accA = MFMA16(whi[2], bhi[2], accA);
            accB = MFMA16(whi[1], bhi[1], accB);
            accA = MFMA16(whi[4], bhi[4], accA);
            accB = MFMA16(whi[3], bhi[3], accB);
            accB = MFMA16(whi[5], bhi[5], accB);

            // in-lane epilogue: cell (m = n, u = 4wv+quad)
            const int u = 4 * wv + quad;
            if (u < H2) {
                float gi = accA[0] + accB[0];
                float gf = accA[1] + accB[1];
                float gc = accA[2] + accB[2];
                float go = accA[3] + accB[3];
                float cn = sigf(gf) * cst + sigf(gi) * tanhfast(gc);
                float h  = sigf(go) * tanhfast(cn);
                cst = cn;
                unsigned short hh = f2bf(h);
                hB_hi[pp ^ 1][frag_off(n, u)] = (short)hh;
                y2[((size_t)(b0 + n) * Tz + t) * 42 + dir * H2 + u] = hh;
            }
        }
    }
}

// ---------------------------------------------------------------------------
// Dense head: thread per (b,t). Weights via uniform scalar loads.
// ---------------------------------------------------------------------------
__global__ __launch_bounds__(256) void k_dense(
    const unsigned short* __restrict__ y2,
    const float* __restrict__ wd1, const float* __restrict__ bd1,
    const float* __restrict__ wd2, const float* __restrict__ bd2,
    const float* __restrict__ wo,  const float* __restrict__ bo,
    float* __restrict__ out)
{
    int idx = blockIdx.x * 256 + threadIdx.x;
    if (idx >= Bz * Tz) return;
    const unsigned int* row = (const unsigned int*)&y2[(size_t)idx * 42];

    float v[42];
#pragma unroll
    for (int j = 0; j < 21; ++j) {
        unsigned int p = row[j];
        v[2 * j]     = bf2f((unsigned short)(p & 0xFFFFu));
        v[2 * j + 1] = bf2f((unsigned short)(p >> 16));
    }

    float h1[30];
#pragma unroll
    for (int o = 0; o < 30; ++o) {
        float s = bd1[o];
#pragma unroll
        for (int j = 0; j < 42; ++j) s = fmaf(v[j], wd1[o * 42 + j], s);
        h1[o] = fmaxf(s, 0.0f);
    }
    float outv = bo[0];
#pragma unroll
    for (int o = 0; o < 20; ++o) {
        float s = bd2[o];
#pragma unroll
        for (int j = 0; j < 30; ++j) s = fmaf(h1[j], wd2[o * 30 + j], s);
        outv = fmaf(fmaxf(s, 0.0f), wo[o], outv);
    }
    out[idx] = outv;
}

// ---------------------------------------------------------------------------
extern "C" void kernel_launch(void* const* d_in, const int* in_sizes, int n_in,
                              void* d_out, int out_size, void* d_ws, size_t ws_size,
                              hipStream_t stream)
{
    const float* x      = (const float*)d_in[0];
    const float* w1f_ih = (const float*)d_in[1];
    const float* w1f_hh = (const float*)d_in[2];
    const float* b1f_ih = (const float*)d_in[3];
    const float* b1f_hh = (const float*)d_in[4];
    const float* w1b_ih = (const float*)d_in[5];
    const float* w1b_hh = (const float*)d_in[6];
    const float* b1b_ih = (const float*)d_in[7];
    const float* b1b_hh = (const float*)d_in[8];
    const float* w2f_ih = (const float*)d_in[9];
    const float* w2f_hh = (const float*)d_in[10];
    const float* b2f_ih = (const float*)d_in[11];
    const float* b2f_hh = (const float*)d_in[12];
    const float* w2b_ih = (const float*)d_in[13];
    const float* w2b_hh = (const float*)d_in[14];
    const float* b2b_ih = (const float*)d_in[15];
    const float* b2b_hh = (const float*)d_in[16];
    const float* wd1    = (const float*)d_in[17];
    const float* bd1    = (const float*)d_in[18];
    const float* wd2    = (const float*)d_in[19];
    const float* bd2    = (const float*)d_in[20];
    const float* wo     = (const float*)d_in[21];
    const float* bo     = (const float*)d_in[22];
    float* out = (float*)d_out;

    // Workspace: y1 bf16 [T][128][140][16] (192.7 MB) + y2 bf16 [B][T][42] (57.8 MB)
    const size_t y1_elems = (size_t)Tz * 128 * 2240;
    const size_t y2_elems = (size_t)Bz * Tz * 42;
    if (ws_size < (y1_elems + y2_elems) * 2) return;

    unsigned short* y1 = (unsigned short*)d_ws;
    unsigned short* y2 = y1 + y1_elems;

    hipLaunchKernelGGL(k_lstm1, dim3(512), dim3(576), 0, stream,
                       x, w1f_ih, w1f_hh, b1f_ih, b1f_hh,
                       w1b_ih, w1b_hh, b1b_ih, b1b_hh, y1);
    hipLaunchKernelGGL(k_lstm2, dim3(256), dim3(512), 0, stream,
                       y1, w2f_ih, w2f_hh, b2f_ih, b2f_hh,
                       w2b_ih, w2b_hh, b2b_ih, b2b_hh, y2);
    hipLaunchKernelGGL(k_dense, dim3((Bz * Tz + 255) / 256), dim3(256), 0, stream,
                       y2, wd1, bd1, wd2, bd2, wo, bo, out);
}